// Round 4
// baseline (58.504 us; speedup 1.0000x reference)
//
#include <hip/hip_runtime.h>
#include <hip/hip_bf16.h>
#include <math.h>

namespace {

constexpr int L   = 64;    // steps
constexpr int NH  = 256;   // nhid
constexpr int NC  = 64;    // cache_N
constexpr int BSZ = 32;

typedef float f32x16 __attribute__((ext_vector_type(16)));
typedef short bf16x8 __attribute__((ext_vector_type(8)));   // 8 bf16 in 4 VGPRs

// Split 8 fp32 (two float4) into hi/lo bf16x8 fragments: x = hi + lo + O(2^-18 x).
// Uses the compiler's f32->bf16 RNE cast path (emits v_cvt_pk_bf16_f32 pairs).
__device__ inline void split8(const float4 x0, const float4 x1,
                              bf16x8& hi, bf16x8& lo) {
  float f[8];
  *(float4*)(f)     = x0;
  *(float4*)(f + 4) = x1;
#pragma unroll
  for (int q = 0; q < 8; ++q) {
    const __hip_bfloat16 h = __float2bfloat16(f[q]);        // RNE
    unsigned short hu;
    __builtin_memcpy(&hu, &h, 2);
    const float hf = __builtin_bit_cast(float, (unsigned)hu << 16);
    const __hip_bfloat16 l = __float2bfloat16(f[q] - hf);   // exact residual, RNE
    unsigned short lu;
    __builtin_memcpy(&lu, &l, 2);
    hi[q] = (short)hu;
    lo[q] = (short)lu;
  }
}

// Block = 128 threads = 2 waves, one (b, n). Wave w computes the 64x32 C half
// C[0:64, w*32:(w+1)*32] = Q_b(64x256) . K rows[w*32..]^T via split-bf16 MFMA
// (3 passes), then max-reduce; waves combine through a 2-entry LDS max.
// C fragment layout is irrelevant (max-reduce), and the A/B k-pairing is
// consistent by construction (same r/h8 mapping for both operands).
__global__ __launch_bounds__(128, 4) void attmax_mfma(
    const float* __restrict__ query,   // (1, 64, 32, 256)
    const float* __restrict__ keys,    // (64, 32, 16384)
    float* __restrict__ out)           // out[b*64+n] = att
{
  __shared__ float wmax[2];

  const int n    = blockIdx.x & 63;
  const int b    = blockIdx.x >> 6;
  const int w    = threadIdx.x >> 6;   // wave id: which 32-col K half
  const int lane = threadIdx.x & 63;
  const int r    = lane & 31;          // row within 32-tile
  const int h8   = (lane >> 5) * 8;    // k-subrange selector

  // Q element (i,k): query[(i*32 + b)*256 + k]   (row stride 32 KB)
  // K element (j,k): keys[(n*32 + b)*16384 + j*256 + k]  (row stride 1 KB)
  const float* qb = query + (size_t)b * NH;
  const float* kb = keys + ((size_t)n * BSZ + b) * (size_t)(L * NH)
                  + (size_t)(w * 32) * NH;   // this wave's 32 K rows

  f32x16 acc[2];
#pragma unroll
  for (int i = 0; i < 2; ++i)
#pragma unroll
    for (int e = 0; e < 16; ++e) acc[i][e] = 0.f;

#pragma unroll 2
  for (int kc = 0; kc < NH; kc += 16) {
    // Issue all 6 global loads first, then convert, then MFMA.
    float4 xq[2][2], xk[2];
#pragma unroll
    for (int t = 0; t < 2; ++t) {
      const float* qs = qb + (size_t)(t * 32 + r) * (BSZ * NH) + kc + h8;
      xq[t][0] = *(const float4*)(qs);
      xq[t][1] = *(const float4*)(qs + 4);
    }
    {
      const float* ks = kb + (size_t)r * NH + kc + h8;
      xk[0] = *(const float4*)(ks);
      xk[1] = *(const float4*)(ks + 4);
    }
    bf16x8 ah[2], al[2], bh, bl;
#pragma unroll
    for (int t = 0; t < 2; ++t) split8(xq[t][0], xq[t][1], ah[t], al[t]);
    split8(xk[0], xk[1], bh, bl);

#pragma unroll
    for (int i = 0; i < 2; ++i) {
      acc[i] = __builtin_amdgcn_mfma_f32_32x32x16_bf16(al[i], bh, acc[i], 0, 0, 0);
      acc[i] = __builtin_amdgcn_mfma_f32_32x32x16_bf16(ah[i], bl, acc[i], 0, 0, 0);
      acc[i] = __builtin_amdgcn_mfma_f32_32x32x16_bf16(ah[i], bh, acc[i], 0, 0, 0);
    }
  }

  float m = -INFINITY;
#pragma unroll
  for (int i = 0; i < 2; ++i)
#pragma unroll
    for (int e = 0; e < 16; ++e) m = fmaxf(m, acc[i][e]);

#pragma unroll
  for (int off = 1; off < 64; off <<= 1)
    m = fmaxf(m, __shfl_xor(m, off, 64));

  if (lane == 0) wmax[w] = m;
  __syncthreads();
  if (threadIdx.x == 0) out[(size_t)b * NC + n] = fmaxf(wmax[0], wmax[1]);
}

// One block (64 lanes) per batch b: 8 rounds of argmax with lowest-index
// tie-break (matches jax.lax.top_k stability). Indices written as floats.
__global__ __launch_bounds__(64) void topk_kernel(float* __restrict__ out) {
  const int b = blockIdx.x;
  const int l = threadIdx.x;
  float v = out[b * NC + l];
#pragma unroll
  for (int k = 0; k < 8; ++k) {
    float bv = v;
    int bi = l;
#pragma unroll
    for (int off = 1; off < 64; off <<= 1) {
      const float ov = __shfl_xor(bv, off, 64);
      const int oi = __shfl_xor(bi, off, 64);
      if (ov > bv || (ov == bv && oi < bi)) { bv = ov; bi = oi; }
    }
    if (l == 0) out[BSZ * NC + k * BSZ + b] = (float)bi;  // (topk, bsz) layout
    if (l == bi) v = -INFINITY;
  }
}

}  // namespace

extern "C" void kernel_launch(void* const* d_in, const int* in_sizes, int n_in,
                              void* d_out, int out_size, void* d_ws, size_t ws_size,
                              hipStream_t stream) {
  const float* query = (const float*)d_in[0];
  const float* keys  = (const float*)d_in[1];
  // d_in[2] (values) is dead code in the max_pooling branch — never read.
  float* out = (float*)d_out;

  attmax_mfma<<<dim3(BSZ * NC), dim3(128), 0, stream>>>(query, keys, out);
  topk_kernel<<<dim3(BSZ), dim3(64), 0, stream>>>(out);
}

// Round 5
// 38.992 us; speedup vs baseline: 1.5004x; 1.5004x over previous
//
#include <hip/hip_runtime.h>
#include <hip/hip_bf16.h>
#include <math.h>

namespace {

constexpr int L   = 64;    // steps
constexpr int NH  = 256;   // nhid
constexpr int NC  = 64;    // cache_N
constexpr int BSZ = 32;

typedef float f32x16 __attribute__((ext_vector_type(16)));
typedef short bf16x8 __attribute__((ext_vector_type(8)));   // 8 bf16 in 4 VGPRs

// Split 8 fp32 (two float4) into hi/lo bf16x8: x = hi + lo + O(2^-18 x).
__device__ inline void split8(const float4 x0, const float4 x1,
                              bf16x8& hi, bf16x8& lo) {
  float f[8];
  *(float4*)(f)     = x0;
  *(float4*)(f + 4) = x1;
#pragma unroll
  for (int q = 0; q < 8; ++q) {
    const __hip_bfloat16 h = __float2bfloat16(f[q]);        // RNE
    unsigned short hu;
    __builtin_memcpy(&hu, &h, 2);
    const float hf = __builtin_bit_cast(float, (unsigned)hu << 16);
    const __hip_bfloat16 l = __float2bfloat16(f[q] - hf);   // exact residual, RNE
    unsigned short lu;
    __builtin_memcpy(&lu, &l, 2);
    hi[q] = (short)hu;
    lo[q] = (short)lu;
  }
}

// Block = 256 threads = 4 waves, handles (b, 4 consecutive n). Q_b is staged
// once into LDS as split-bf16 in fragment-linear order; then each wave
// independently computes C(64x64) = Q_b . K_{n}^T for its own n via 3-pass
// split-bf16 MFMA (A from LDS, B direct from global with depth-2 prefetch),
// and max-reduces. No main-loop barriers, no K duplication across waves.
__global__ __launch_bounds__(256, 2) void attmax_mfma(
    const float* __restrict__ query,   // (1, 64, 32, 256)
    const float* __restrict__ keys,    // (64, 32, 16384)
    float* __restrict__ out)           // out[b*64+n] = att
{
  // Fragment-linear split-bf16 Q: slot(it,kc,lane) -> 8 bf16 (16B)
  __shared__ __align__(16) short Qhi[2 * 16 * 64 * 8];   // 32 KB
  __shared__ __align__(16) short Qlo[2 * 16 * 64 * 8];   // 32 KB

  // XCD-affine remap: blocks sharing b land on the same XCD (bid%8 == b%8).
  const unsigned X = blockIdx.x;            // 0..511
  const int b = ((X >> 7) << 3) | (X & 7);  // 0..31
  const int g = (X >> 3) & 15;              // n-group 0..15

  const int tid  = threadIdx.x;
  const int w    = tid >> 6;          // wave id 0..3 -> n = g*4 + w
  const int lane = tid & 63;
  const int r    = lane & 31;         // A/B row within 32-tile
  const int h    = lane >> 5;         // k-subrange selector (0/1)

  // ---- Stage Q_b: 2048 fragment slots, 8 fp32 each -> split -> LDS ----
  // slot s: it = s>>10, kc = (s>>6)&15, l = s&63 (row l&31, half l>>5)
  for (int s = tid; s < 2048; s += 256) {
    const int it = s >> 10;
    const int kc = (s >> 6) & 15;
    const int sl = s & 63;
    const int row = it * 32 + (sl & 31);
    const int kof = kc * 16 + (sl >> 5) * 8;
    const float* src = query + ((size_t)row * BSZ + b) * NH + kof;
    bf16x8 hi, lo;
    split8(*(const float4*)src, *(const float4*)(src + 4), hi, lo);
    *(bf16x8*)&Qhi[s * 8] = hi;
    *(bf16x8*)&Qlo[s * 8] = lo;
  }
  __syncthreads();

  // ---- Main loop: wave-private n ----
  const int n = g * 4 + w;
  const float* kb = keys + ((size_t)n * BSZ + b) * (size_t)(L * NH);
  // lane's K pointer for row r of j-tile 0, k-slice h*8
  const float* kp = kb + (size_t)r * NH + h * 8;

  f32x16 acc[2][2];
#pragma unroll
  for (int i = 0; i < 2; ++i)
#pragma unroll
    for (int j = 0; j < 2; ++j)
#pragma unroll
      for (int e = 0; e < 16; ++e) acc[i][j][e] = 0.f;

  float4 bufA[4], bufB[4];   // [jt*2 + half]: 8 fp32 per jt per lane

#define LOAD_K(buf, kc)                                                  \
  do {                                                                   \
    const float* p0 = kp + (kc) * 16;                                    \
    (buf)[0] = *(const float4*)(p0);                                     \
    (buf)[1] = *(const float4*)(p0 + 4);                                 \
    const float* p1 = p0 + 32 * NH;                                      \
    (buf)[2] = *(const float4*)(p1);                                     \
    (buf)[3] = *(const float4*)(p1 + 4);                                 \
  } while (0)

#define COMPUTE(buf, kc)                                                 \
  do {                                                                   \
    bf16x8 bh0, bl0, bh1, bl1;                                           \
    split8((buf)[0], (buf)[1], bh0, bl0);                                \
    split8((buf)[2], (buf)[3], bh1, bl1);                                \
    bf16x8 ah[2], al[2];                                                 \
    _Pragma("unroll")                                                    \
    for (int it = 0; it < 2; ++it) {                                     \
      const int slot = ((it * 16 + (kc)) * 64 + lane) * 8;               \
      ah[it] = *(const bf16x8*)&Qhi[slot];                               \
      al[it] = *(const bf16x8*)&Qlo[slot];                               \
    }                                                                    \
    _Pragma("unroll")                                                    \
    for (int it = 0; it < 2; ++it) {                                     \
      acc[it][0] = __builtin_amdgcn_mfma_f32_32x32x16_bf16(al[it], bh0, acc[it][0], 0, 0, 0); \
      acc[it][0] = __builtin_amdgcn_mfma_f32_32x32x16_bf16(ah[it], bl0, acc[it][0], 0, 0, 0); \
      acc[it][0] = __builtin_amdgcn_mfma_f32_32x32x16_bf16(ah[it], bh0, acc[it][0], 0, 0, 0); \
      acc[it][1] = __builtin_amdgcn_mfma_f32_32x32x16_bf16(al[it], bh1, acc[it][1], 0, 0, 0); \
      acc[it][1] = __builtin_amdgcn_mfma_f32_32x32x16_bf16(ah[it], bl1, acc[it][1], 0, 0, 0); \
      acc[it][1] = __builtin_amdgcn_mfma_f32_32x32x16_bf16(ah[it], bh1, acc[it][1], 0, 0, 0); \
    }                                                                    \
  } while (0)

  LOAD_K(bufA, 0);
#pragma unroll
  for (int kc = 0; kc < 16; kc += 2) {
    if (kc + 1 < 16) LOAD_K(bufB, kc + 1);
    COMPUTE(bufA, kc);
    if (kc + 2 < 16) LOAD_K(bufA, kc + 2);
    COMPUTE(bufB, kc + 1);
  }
#undef LOAD_K
#undef COMPUTE

  float m = -INFINITY;
#pragma unroll
  for (int i = 0; i < 2; ++i)
#pragma unroll
    for (int j = 0; j < 2; ++j)
#pragma unroll
      for (int e = 0; e < 16; ++e) m = fmaxf(m, acc[i][j][e]);

#pragma unroll
  for (int off = 1; off < 64; off <<= 1)
    m = fmaxf(m, __shfl_xor(m, off, 64));

  if (lane == 0) out[(size_t)b * NC + n] = m;
}

// One block (64 lanes) per batch b: 8 rounds of argmax with lowest-index
// tie-break (matches jax.lax.top_k stability). Indices written as floats.
__global__ __launch_bounds__(64) void topk_kernel(float* __restrict__ out) {
  const int b = blockIdx.x;
  const int l = threadIdx.x;
  float v = out[b * NC + l];
#pragma unroll
  for (int k = 0; k < 8; ++k) {
    float bv = v;
    int bi = l;
#pragma unroll
    for (int off = 1; off < 64; off <<= 1) {
      const float ov = __shfl_xor(bv, off, 64);
      const int oi = __shfl_xor(bi, off, 64);
      if (ov > bv || (ov == bv && oi < bi)) { bv = ov; bi = oi; }
    }
    if (l == 0) out[BSZ * NC + k * BSZ + b] = (float)bi;  // (topk, bsz) layout
    if (l == bi) v = -INFINITY;
  }
}

}  // namespace

extern "C" void kernel_launch(void* const* d_in, const int* in_sizes, int n_in,
                              void* d_out, int out_size, void* d_ws, size_t ws_size,
                              hipStream_t stream) {
  const float* query = (const float*)d_in[0];
  const float* keys  = (const float*)d_in[1];
  // d_in[2] (values) is dead code in the max_pooling branch — never read.
  float* out = (float*)d_out;

  attmax_mfma<<<dim3(512), dim3(256), 0, stream>>>(query, keys, out);
  topk_kernel<<<dim3(BSZ), dim3(64), 0, stream>>>(out);
}